// Round 9
// baseline (1351.882 us; speedup 1.0000x reference)
//
#include <hip/hip_runtime.h>
#include <hip/hip_bf16.h>

// ---------------- problem constants (fixed by reference) ----------------
#define NATOM 50000
#define NEDGE 200000
#define HALF  100000
#define DV    133
#define DE    14
#define DH    256
#define KVP   160   // pad 133/147 -> 160

typedef __bf16  bf16x8 __attribute__((ext_vector_type(8)));
typedef __bf16  bf16x4 __attribute__((ext_vector_type(4)));
typedef float   f32x4  __attribute__((ext_vector_type(4)));

enum { EPI_RELU = 0, EPI_ADDBASE = 1, EPI_FUSE = 2, EPI_NONE = 3, EPI_RELUADD = 4 };
enum { AM_PLAIN = 0, AM_GATE = 1, AM_GDIFF = 2, AM_VF32 = 3, AM_XB = 4, AM_F32 = 5 };

// async global->LDS, 16B per lane; LDS dest = uniform base + lane*16
__device__ __forceinline__ void gll16(const void* g, void* l) {
    __builtin_amdgcn_global_load_lds(
        (const __attribute__((address_space(1))) unsigned int*)g,
        (__attribute__((address_space(3))) unsigned int*)l, 16, 0, 0);
}
// full drain (vmcnt+lgkmcnt) BEFORE barrier: guarantees global_load_lds and
// ds_write data is LDS-resident before any wave crosses (fixed R7 replay race).
__device__ __forceinline__ void drain_barrier() {
    __builtin_amdgcn_s_waitcnt(0);
    __syncthreads();
}

// ---------------- tiled GEMM: C[rows,256] = epi(A' @ W[256,K]^T) ----------
// BM=128, BN=128 (blk&1 = col half), BK=KSTEP (32 or 64), 256 thr / 4 waves
// (2x2 of 64x64, acc=16 f32x4). Per K-iter: B staged via global_load_lds;
// A staged via global_load_lds (PLAIN) or fused synthesis + ds_write.
// LDS tiles row-major [128][KSTEP], no padding (gll contiguity rule).
// Row map: local gr -> global (gr < part0 ? off0+gr : off1+gr-part0).
struct GArgs {
    const __bf16* A; int lda;
    const float* asumf; const __bf16* amaxb;
    const __bf16* HbG; const int* vidx; const int* rev;
    const float* Vf; const float* Ef;
    const __bf16* W; int ldw;
    const __bf16* base; __bf16* C; float* Cf;
    int Mloc; int part0; int off0; int off1;
};

template<int AMODE, int EPI, int CLOC, int STF32, int KITERS, int KSTEP>
__global__ __launch_bounds__(256, 3) void gemm128(GArgs g, int nblk) {
    __shared__ __bf16 Alds[128 * KSTEP];
    __shared__ __bf16 Blds[128 * KSTEP];
    const int tid  = threadIdx.x;
    const int lane = tid & 63, wv = tid >> 6;
    const int quad = lane >> 4, l16 = lane & 15;
    const int wr = (wv >> 1) * 64, wc = (wv & 1) * 64;
    constexpr int RPC = 512 / KSTEP;       // rows per gll call (1 KB each)
    constexpr int CPW = KSTEP / 16;        // gll calls per wave per tile
    constexpr int LPR = 64 / RPC;          // lanes per row in a gll call
    const int lrow = lane / LPR, lu = lane % LPR;

    for (int blk = blockIdx.x; blk < nblk; blk += gridDim.x) {
        const int ch = blk >> 1, half = blk & 1;
        const int gr0  = ch * 128;
        const int colb = half * 128;

        // synth modes: thread stages row rs, half-row seg (KSTEP/2 elems)
        const int rs = tid >> 1, seg = tid & 1;
        const float *sp = nullptr; const __bf16 *hp = nullptr, *mp = nullptr;
        const float *vp = nullptr, *ep = nullptr;
        if (AMODE != AM_PLAIN) {
            int grs = gr0 + rs; if (grs > g.Mloc - 1) grs = g.Mloc - 1;
            const int maps = (grs < g.part0) ? g.off0 + grs : g.off1 + grs - g.part0;
            if (AMODE == AM_GATE)  { sp = g.asumf + (size_t)maps * DH; mp = g.amaxb + (size_t)maps * DH; }
            if (AMODE == AM_GDIFF) { sp = g.asumf + (size_t)g.vidx[maps] * DH; hp = g.HbG + (size_t)g.rev[maps] * DH; }
            if (AMODE == AM_F32)   { sp = g.asumf + (size_t)maps * DH; }
            if (AMODE == AM_VF32)  { vp = g.Vf + (size_t)maps * DV; }
            if (AMODE == AM_XB)    { vp = g.Vf + (size_t)g.vidx[maps] * DV; ep = g.Ef + (size_t)maps * DE; }
        }

        f32x4 acc[16];
#pragma unroll
        for (int i = 0; i < 16; ++i) acc[i] = (f32x4){0.f, 0.f, 0.f, 0.f};

        for (int kk = 0; kk < KITERS; ++kk) {
            // ---- stage B ----
#pragma unroll
            for (int s = 0; s < CPW; ++s) {
                int cl = (wv * CPW + s) * RPC + lrow;
                gll16(g.W + (size_t)(colb + cl) * g.ldw + kk * KSTEP + lu * 8,
                      Blds + (wv * CPW + s) * 512);
            }
            // ---- stage A ----
            if (AMODE == AM_PLAIN) {
#pragma unroll
                for (int s = 0; s < CPW; ++s) {
                    int r = (wv * CPW + s) * RPC + lrow;
                    int gra = gr0 + r; if (gra > g.Mloc - 1) gra = g.Mloc - 1;
                    gll16(g.A + (size_t)gra * g.lda + kk * KSTEP + lu * 8,
                          Alds + (wv * CPW + s) * 512);
                }
            } else {
#pragma unroll
                for (int sc = 0; sc < KSTEP / 32; ++sc) {
                    const int co = seg * (KSTEP / 2) + sc * 16;   // offset in tile row
                    const int cb = kk * KSTEP + co;               // global k offset
                    bf16x8 o0, o1;
                    if (AMODE == AM_GATE || AMODE == AM_GDIFF || AMODE == AM_F32) {
                        f32x4 s0 = *(const f32x4*)(sp + cb);
                        f32x4 s1 = *(const f32x4*)(sp + cb + 4);
                        f32x4 s2 = *(const f32x4*)(sp + cb + 8);
                        f32x4 s3 = *(const f32x4*)(sp + cb + 12);
                        if (AMODE == AM_GATE) {
                            bf16x8 m0 = *(const bf16x8*)(mp + cb);
                            bf16x8 m1 = *(const bf16x8*)(mp + cb + 8);
#pragma unroll
                            for (int j = 0; j < 4; ++j) {
                                o0[j]     = (__bf16)(s0[j] * (float)m0[j]);
                                o0[4 + j] = (__bf16)(s1[j] * (float)m0[4 + j]);
                                o1[j]     = (__bf16)(s2[j] * (float)m1[j]);
                                o1[4 + j] = (__bf16)(s3[j] * (float)m1[4 + j]);
                            }
                        } else if (AMODE == AM_GDIFF) {
                            bf16x8 h0 = *(const bf16x8*)(hp + cb);
                            bf16x8 h1 = *(const bf16x8*)(hp + cb + 8);
#pragma unroll
                            for (int j = 0; j < 4; ++j) {
                                o0[j]     = (__bf16)(s0[j] - (float)h0[j]);
                                o0[4 + j] = (__bf16)(s1[j] - (float)h0[4 + j]);
                                o1[j]     = (__bf16)(s2[j] - (float)h1[j]);
                                o1[4 + j] = (__bf16)(s3[j] - (float)h1[4 + j]);
                            }
                        } else {
#pragma unroll
                            for (int j = 0; j < 4; ++j) {
                                o0[j]     = (__bf16)s0[j];
                                o0[4 + j] = (__bf16)s1[j];
                                o1[j]     = (__bf16)s2[j];
                                o1[4 + j] = (__bf16)s3[j];
                            }
                        }
                    } else {   // AM_VF32 / AM_XB: f32 rows width 133(+14), K-padded
                        if (cb + 16 <= 128) {    // fully inside V row
                            f32x4 x0, x1, x2, x3;
                            __builtin_memcpy(&x0, vp + cb, 16);
                            __builtin_memcpy(&x1, vp + cb + 4, 16);
                            __builtin_memcpy(&x2, vp + cb + 8, 16);
                            __builtin_memcpy(&x3, vp + cb + 12, 16);
#pragma unroll
                            for (int j = 0; j < 4; ++j) {
                                o0[j] = (__bf16)x0[j]; o0[4 + j] = (__bf16)x1[j];
                                o1[j] = (__bf16)x2[j]; o1[4 + j] = (__bf16)x3[j];
                            }
                        } else {                 // boundary: per-element guard
#pragma unroll
                            for (int j = 0; j < 8; ++j) {
                                int c0 = cb + j, c1 = cb + 8 + j;
                                float y0 = 0.f, y1 = 0.f;
                                if (c0 < DV) y0 = vp[c0];
                                else if (AMODE == AM_XB && c0 < DV + DE) y0 = ep[c0 - DV];
                                if (c1 < DV) y1 = vp[c1];
                                else if (AMODE == AM_XB && c1 < DV + DE) y1 = ep[c1 - DV];
                                o0[j] = (__bf16)y0; o1[j] = (__bf16)y1;
                            }
                        }
                    }
                    *(bf16x8*)(Alds + rs * KSTEP + co)     = o0;
                    *(bf16x8*)(Alds + rs * KSTEP + co + 8) = o1;
                }
            }
            drain_barrier();

            // ---- compute: (KSTEP/32) x 16 MFMA ----
#pragma unroll
            for (int sub = 0; sub < KSTEP / 32; ++sub) {
                bf16x8 af[4], bfv[4];
#pragma unroll
                for (int m = 0; m < 4; ++m)
                    af[m] = *(const bf16x8*)(Alds + (wr + m * 16 + l16) * KSTEP + sub * 32 + quad * 8);
#pragma unroll
                for (int n = 0; n < 4; ++n)
                    bfv[n] = *(const bf16x8*)(Blds + (wc + n * 16 + l16) * KSTEP + sub * 32 + quad * 8);
#pragma unroll
                for (int m = 0; m < 4; ++m)
#pragma unroll
                    for (int n = 0; n < 4; ++n)
                        acc[m * 4 + n] = __builtin_amdgcn_mfma_f32_16x16x32_bf16(
                            af[m], bfv[n], acc[m * 4 + n], 0, 0, 0);
            }
            drain_barrier();
        }

        // ---- epilogue: wave's 64x64 patch ----
#pragma unroll
        for (int m = 0; m < 4; ++m)
#pragma unroll
        for (int n = 0; n < 4; ++n)
#pragma unroll
        for (int r = 0; r < 4; ++r) {
            int gr = gr0 + wr + m * 16 + quad * 4 + r;
            if (gr < g.Mloc) {
                int mapped = (gr < g.part0) ? g.off0 + gr : g.off1 + gr - g.part0;
                int crow = CLOC ? gr : mapped;
                int col = colb + wc + n * 16 + l16;
                size_t co = (size_t)crow * DH + col;
                float v = acc[m * 4 + n][r];
                float res;
                if (EPI == EPI_RELU)       res = v > 0.f ? v : 0.f;
                else if (EPI == EPI_NONE)  res = v;
                else {
                    float b = (float)g.base[(size_t)mapped * DH + col];
                    if (EPI == EPI_ADDBASE)      res = b + v;
                    else if (EPI == EPI_FUSE)    res = b + (v > 0.f ? v : 0.f);
                    else /* EPI_RELUADD */       { res = b + v; res = res > 0.f ? res : 0.f; }
                }
                if (STF32) g.Cf[co] = res;
                else       g.C[co]  = (__bf16)res;
            }
        }
    }
}

// ---------------- CSR build (once per launch; widx constant) ----------------
__global__ void count_deg(const int* __restrict__ widx, int* __restrict__ cnt) {
    int e = blockIdx.x * 256 + threadIdx.x;
    if (e < NEDGE) atomicAdd(&cnt[widx[e]], 1);
}

// 3-phase parallel exclusive scan over NATOM counts -> rowptr
#define SCAN_BLOCKS ((NATOM + 255) / 256)   // 196
__global__ __launch_bounds__(256) void scan_p1(const int* __restrict__ cnt,
                                               int* __restrict__ rowptr,
                                               int* __restrict__ bsum) {
    __shared__ int sh[256];
    const int tid = threadIdx.x;
    int idx = blockIdx.x * 256 + tid;
    int v = (idx < NATOM) ? cnt[idx] : 0;
    sh[tid] = v;
    __syncthreads();
    for (int off = 1; off < 256; off <<= 1) {
        int t = (tid >= off) ? sh[tid - off] : 0;
        __syncthreads();
        sh[tid] += t;
        __syncthreads();
    }
    if (idx < NATOM) rowptr[idx] = sh[tid] - v;   // exclusive within block
    if (tid == 255) bsum[blockIdx.x] = sh[255];
}
__global__ __launch_bounds__(256) void scan_p2(int* __restrict__ bsum,
                                               int* __restrict__ rowptr) {
    __shared__ int sh[256];
    const int tid = threadIdx.x;
    int v = (tid < SCAN_BLOCKS) ? bsum[tid] : 0;
    sh[tid] = v;
    __syncthreads();
    for (int off = 1; off < 256; off <<= 1) {
        int t = (tid >= off) ? sh[tid - off] : 0;
        __syncthreads();
        sh[tid] += t;
        __syncthreads();
    }
    if (tid < SCAN_BLOCKS) bsum[tid] = sh[tid] - v;  // exclusive block offsets
    if (tid == 0) rowptr[NATOM] = NEDGE;
}
__global__ __launch_bounds__(256) void scan_p3(const int* __restrict__ bsum,
                                               int* __restrict__ rowptr) {
    int idx = blockIdx.x * 256 + threadIdx.x;
    if (idx < NATOM) rowptr[idx] += bsum[blockIdx.x];
}

__global__ void fill_csr(const int* __restrict__ widx, int* __restrict__ cursor,
                         int* __restrict__ eid) {
    int e = blockIdx.x * 256 + threadIdx.x;
    if (e >= NEDGE) return;
    int pos = atomicAdd(&cursor[widx[e]], 1);
    eid[pos] = e;
}

// ---------------- segmented sum+max, one wave per atom, no atomics ----------
// f32 sums (stored f32), bf16 max (exact). H_b >= 0 so 0-init max is exact;
// empty segments -> 0 (ref rule). eid prefetched one iter ahead to overlap
// the eid->Hb dependent-load chain.
template<int WITHMAX>
__global__ __launch_bounds__(256) void seg_reduce(
    const __bf16* __restrict__ Hb, const int* __restrict__ rowptr,
    const int* __restrict__ eid,
    float* __restrict__ asum, __bf16* __restrict__ amaxb)
{
    int a = blockIdx.x * 4 + (threadIdx.x >> 6);
    if (a >= NATOM) return;
    const int lane = threadIdx.x & 63;
    const int beg = rowptr[a], end = rowptr[a + 1];
    float s0 = 0.f, s1 = 0.f, s2 = 0.f, s3 = 0.f;
    float m0 = 0.f, m1 = 0.f, m2 = 0.f, m3 = 0.f;
    int en = (beg < end) ? eid[beg] : 0;
    for (int i = beg; i < end; ++i) {
        int e = en;
        en = (i + 1 < end) ? eid[i + 1] : 0;
        bf16x4 h = *(const bf16x4*)(Hb + (size_t)e * DH + lane * 4);
        float v0 = (float)h[0], v1 = (float)h[1], v2 = (float)h[2], v3 = (float)h[3];
        s0 += v0; s1 += v1; s2 += v2; s3 += v3;
        if (WITHMAX) {
            m0 = fmaxf(m0, v0); m1 = fmaxf(m1, v1);
            m2 = fmaxf(m2, v2); m3 = fmaxf(m3, v3);
        }
    }
    size_t o = (size_t)a * DH + lane * 4;
    *(f32x4*)(asum + o) = (f32x4){s0, s1, s2, s3};
    if (WITHMAX) {
        bf16x4 mv; mv[0] = (__bf16)m0; mv[1] = (__bf16)m1; mv[2] = (__bf16)m2; mv[3] = (__bf16)m3;
        *(bf16x4*)(amaxb + o) = mv;
    }
}

// ---------------- weight pad/convert: dst[256,KD] <- f32 src[256 rows, srcld] --
__global__ void pad_w2(const float* __restrict__ src, __bf16* __restrict__ dst,
                       int srcld, int coloff, int KS, int KD) {
    int i = blockIdx.x * 256 + threadIdx.x;
    if (i >= 256 * KD) return;
    int n = i / KD, c = i - n * KD;
    dst[i] = (c < KS) ? (__bf16)src[(size_t)n * srcld + coloff + c] : (__bf16)0.f;
}

// ---------------- launcher ----------------
static inline int cdiv(long a, long b) { return (int)((a + b - 1) / b); }
static inline int gsz2(int nblk) { return nblk < 2048 ? nblk : 2048; }

extern "C" void kernel_launch(void* const* d_in, const int* in_sizes, int n_in,
                              void* d_out, int out_size, void* d_ws, size_t ws_size,
                              hipStream_t stream) {
    const float* V    = (const float*)d_in[0];
    const float* Ef   = (const float*)d_in[1];
    const int*   ei   = (const int*)d_in[2];      // [0:E)=v, [E:2E)=w
    const int*   rev  = (const int*)d_in[3];
    const float* Wi_a = (const float*)d_in[4];
    const float* Wi_b = (const float*)d_in[5];
    const float* Wh_a = (const float*)d_in[6];
    const float* Wh_b = (const float*)d_in[7];
    const float* Wf_a = (const float*)d_in[8];
    const float* Wf_b = (const float*)d_in[9];
    const float* Wo   = (const float*)d_in[10];
    float* out = (float*)d_out;

    const int* vidx = ei;
    const int* widx = ei + NEDGE;

    // ---- workspace layout (~245.3 MB, identical to the passing R8 layout) ----
    char* ws = (char*)d_ws;
    __bf16* Hb    = (__bf16*)(ws + 0);            // 102.4M
    __bf16* Ha    = (__bf16*)(ws + 102400000);    // 25.6M
    char*   S     = ws + 128000000;               // 64M scratch
    float*  asum  = (float*)(ws + 192000000);     // 51.2M (f32)
    __bf16* amaxb = (__bf16*)(S + 0);             // 25.6M (dead before Tb live)
    __bf16* Ta    = (__bf16*)(S + 25600000);      // 25.6M
    __bf16* Tb    = (__bf16*)(S + 0);             // 51.2M
    __bf16* T     = (__bf16*)(S + 25600000);      // readout tmp
    int*    bsum  = (int*)S;                      // CSR-build phase only (dead after)
    __bf16* Wia   = (__bf16*)(ws + 243200000);
    __bf16* Wib   = (__bf16*)(ws + 243281920);
    __bf16* Wo1   = (__bf16*)(ws + 243363840);
    __bf16* Wo2   = (__bf16*)(ws + 243445760);
    __bf16* Wha   = (__bf16*)(ws + 243576832);
    __bf16* Whb   = (__bf16*)(ws + 243707904);
    __bf16* Wfa   = (__bf16*)(ws + 243838976);
    __bf16* Wfb   = (__bf16*)(ws + 243970048);
    int*  rowptr  = (int*)(ws + 244101120);
    int*  cursor  = (int*)(ws + 244301312);
    int*  eid     = (int*)(ws + 244501504);
    (void)ws_size;

    // ---- CSR build (parallel scan; bsum lives in S, which is dead here) ----
    hipMemsetAsync(cursor, 0, NATOM * sizeof(int), stream);
    count_deg<<<cdiv(NEDGE, 256), 256, 0, stream>>>(widx, cursor);
    scan_p1<<<SCAN_BLOCKS, 256, 0, stream>>>(cursor, rowptr, bsum);
    scan_p2<<<1, 256, 0, stream>>>(bsum, rowptr);
    scan_p3<<<SCAN_BLOCKS, 256, 0, stream>>>(bsum, rowptr);
    hipMemcpyAsync(cursor, rowptr, NATOM * sizeof(int), hipMemcpyDeviceToDevice, stream);
    fill_csr<<<cdiv(NEDGE, 256), 256, 0, stream>>>(widx, cursor, eid);

    // ---- weights -> bf16 (padded) ----
    pad_w2<<<cdiv(256 * KVP, 256), 256, 0, stream>>>(Wi_a, Wia, DV, 0, DV, KVP);
    pad_w2<<<cdiv(256 * KVP, 256), 256, 0, stream>>>(Wi_b, Wib, DV + DE, 0, DV + DE, KVP);
    pad_w2<<<cdiv(256 * KVP, 256), 256, 0, stream>>>(Wo, Wo1, DV + DH, 0, DV, KVP);
    pad_w2<<<cdiv(256 * DH, 256), 256, 0, stream>>>(Wo, Wo2, DV + DH, DV, DH, DH);
    pad_w2<<<cdiv(256 * DH, 256), 256, 0, stream>>>(Wh_a, Wha, DH, 0, DH, DH);
    pad_w2<<<cdiv(256 * DH, 256), 256, 0, stream>>>(Wh_b, Whb, DH, 0, DH, DH);
    pad_w2<<<cdiv(256 * DH, 256), 256, 0, stream>>>(Wf_a, Wfa, DH, 0, DH, DH);
    pad_w2<<<cdiv(256 * DH, 256), 256, 0, stream>>>(Wf_b, Wfb, DH, 0, DH, DH);

    GArgs ga{};
    ga.asumf = asum; ga.amaxb = amaxb; ga.HbG = Hb; ga.vidx = vidx; ga.rev = rev;
    ga.Vf = V; ga.Ef = Ef;

    // ---- input GEMMs (K=160, BK=32) ----
    {
        int nblk = cdiv(NATOM, 128) * 2;
        ga.W = Wia; ga.ldw = KVP; ga.C = Ha;
        ga.Mloc = NATOM; ga.part0 = NATOM; ga.off0 = 0; ga.off1 = 0;
        gemm128<AM_VF32, EPI_RELU, 0, 0, 5, 32><<<gsz2(nblk), 256, 0, stream>>>(ga, nblk);
    }
    {
        int nblk = cdiv(NEDGE, 128) * 2;
        ga.W = Wib; ga.ldw = KVP; ga.C = Hb;
        ga.Mloc = NEDGE; ga.part0 = NEDGE; ga.off0 = 0; ga.off1 = 0;
        gemm128<AM_XB, EPI_RELU, 0, 0, 5, 32><<<gsz2(nblk), 256, 0, stream>>>(ga, nblk);
    }

    // ---- message passing iterations (K=256, BK=64) ----
    for (int it = 0; it < 2; ++it) {
        seg_reduce<1><<<cdiv(NATOM, 4), 256, 0, stream>>>(Hb, rowptr, eid, asum, amaxb);

        // atoms: Ta = Ha + bf16(asum*amax) @ Wh_a^T ; Ha += relu(Ta @ Wf_a^T)
        {
            int nblk = cdiv(NATOM, 128) * 2;
            ga.W = Wha; ga.ldw = DH; ga.base = Ha; ga.C = Ta;
            ga.Mloc = NATOM; ga.part0 = NATOM; ga.off0 = 0; ga.off1 = 0;
            gemm128<AM_GATE, EPI_ADDBASE, 1, 0, 4, 64><<<gsz2(nblk), 256, 0, stream>>>(ga, nblk);
            ga.A = Ta; ga.lda = DH; ga.W = Wfa; ga.base = Ha; ga.C = Ha;
            gemm128<AM_PLAIN, EPI_FUSE, 0, 0, 4, 64><<<gsz2(nblk), 256, 0, stream>>>(ga, nblk);
        }

        // bonds, 2 pair-closed chunks (rows [c*50K,+50K) U [100K+c*50K,+50K)):
        //   Tb = Hb + bf16(asum[v]-Hb[rev]) @ Wh_b^T ; Hb += relu(Tb @ Wf_b^T).
        // rev maps within each chunk, so later chunks never read updated rows.
        for (int c = 0; c < 2; ++c) {
            int nblk = cdiv(HALF, 128) * 2;
            ga.W = Whb; ga.ldw = DH; ga.base = Hb; ga.C = Tb;
            ga.Mloc = HALF; ga.part0 = HALF / 2; ga.off0 = c * 50000; ga.off1 = HALF + c * 50000;
            gemm128<AM_GDIFF, EPI_ADDBASE, 1, 0, 4, 64><<<gsz2(nblk), 256, 0, stream>>>(ga, nblk);
            ga.A = Tb; ga.lda = DH; ga.W = Wfb; ga.base = Hb; ga.C = Hb;
            gemm128<AM_PLAIN, EPI_FUSE, 0, 0, 4, 64><<<gsz2(nblk), 256, 0, stream>>>(ga, nblk);
        }
    }

    // ---- readout: out = relu(V @ Wo1^T + a_sum @ Wo2^T) ----
    seg_reduce<0><<<cdiv(NATOM, 4), 256, 0, stream>>>(Hb, rowptr, eid, asum, nullptr);
    {
        int nblk = cdiv(NATOM, 128) * 2;
        ga.Mloc = NATOM; ga.part0 = NATOM; ga.off0 = 0; ga.off1 = 0;
        ga.W = Wo1; ga.ldw = KVP; ga.C = T;
        gemm128<AM_VF32, EPI_NONE, 0, 0, 5, 32><<<gsz2(nblk), 256, 0, stream>>>(ga, nblk);
        ga.W = Wo2; ga.ldw = DH; ga.base = T; ga.Cf = out;
        gemm128<AM_F32, EPI_RELUADD, 0, 1, 4, 64><<<gsz2(nblk), 256, 0, stream>>>(ga, nblk);
    }
}